// Round 12
// baseline (256.483 us; speedup 1.0000x reference)
//
#include <hip/hip_runtime.h>
#include <math.h>

typedef __attribute__((ext_vector_type(8))) short short8;
typedef __attribute__((ext_vector_type(4))) float float4v;

#define KDIM  512
#define NQKV  1536

__device__ __forceinline__ unsigned short f2bf(float f) {
    unsigned int u = __float_as_uint(f);
    u += 0x7FFFu + ((u >> 16) & 1u);   // round-to-nearest-even
    return (unsigned short)(u >> 16);
}
__device__ __forceinline__ float bf2f(unsigned short u) {
    return __uint_as_float(((unsigned int)u) << 16);
}

// async global->LDS DMA, 16 B per lane; LDS dest = wave-uniform base + lane*16
__device__ __forceinline__ void gl2lds16(const unsigned short* g, unsigned short* l) {
    __builtin_amdgcn_global_load_lds(
        (const __attribute__((address_space(1))) void*)g,
        (__attribute__((address_space(3))) void*)l, 16, 0, 0);
}

// ---------------- fused cast: x (with roll -32) + both weight matrices ----------
// blocks [0, 16384): x cast+roll ; blocks [16384, 17408): w_qkv / w_proj cast
__global__ __launch_bounds__(256) void cast_all_kernel(const float* __restrict__ x,
                                                       const float* __restrict__ wqkv,
                                                       const float* __restrict__ wproj,
                                                       unsigned short* __restrict__ xb,
                                                       unsigned short* __restrict__ wqkvb,
                                                       unsigned short* __restrict__ wprojb) {
    if (blockIdx.x < 16384) {
        int tid = blockIdx.x * 256 + threadIdx.x;
        int t = tid >> 7;               // token row 0..32767 (shifted order)
        int c = (tid & 127) << 2;
        int b = t >> 12, n = t & 4095;
        int src = (b << 12) | ((n + 32) & 4095);    // roll(x, -32)
        float4 v = *(const float4*)(x + (((size_t)src) << 9) + c);
        ushort4 o;
        o.x = f2bf(v.x); o.y = f2bf(v.y); o.z = f2bf(v.z); o.w = f2bf(v.w);
        *(ushort4*)(xb + (((size_t)t) << 9) + c) = o;
    } else {
        int tid = (blockIdx.x - 16384) * 256 + threadIdx.x;
        int e = tid << 2;
        if (e < NQKV * KDIM) {
            float4 v = *(const float4*)(wqkv + e);
            ushort4 o; o.x = f2bf(v.x); o.y = f2bf(v.y); o.z = f2bf(v.z); o.w = f2bf(v.w);
            *(ushort4*)(wqkvb + e) = o;
        } else {
            int e2 = e - NQKV * KDIM;
            float4 v = *(const float4*)(wproj + e2);
            ushort4 o; o.x = f2bf(v.x); o.y = f2bf(v.y); o.z = f2bf(v.z); o.w = f2bf(v.w);
            *(ushort4*)(wprojb + e2) = o;
        }
    }
}

// ---------------- QKV GEMM: C[M,N] = A[M,K] @ B[N,K]^T ----------------
// 128x128 tile, BK=64 (32 MFMA per barrier pair), 4 waves (2x2).
// Staging via global_load_lds width=16 into flat row-major stride-64 LDS with an
// XOR col-block swizzle (applied on the GLOBAL address side, since the DMA's LDS
// destination must be lane-contiguous): stored block p at row r holds source
// col-block p^(r&7). Fragment ds_read_b128 then hits 8 distinct bank groups.
// NOTE: reg-staged A (fused f32 cast) was tried and is a measured LOSS (103 vs
// 72 us): mixing reg-loads with DMA defeats the vmcnt scheduling (cf. m151).
// Partial software-pipelining of this structure is also a measured no-op
// (m99/m100/m131/m139) - only the full 8-phase template breaks the ceiling.
// XCD-aware bijective swizzle: nwg%8==0; blocks sharing an A-panel (same bm)
// land on the same XCD -> A fetched ~once from HBM (FETCH 135 -> ~30 MB).
template<int N>
__global__ __launch_bounds__(256, 2) void gemm_kernel(
        const unsigned short* __restrict__ A,
        const unsigned short* __restrict__ B,
        unsigned short* __restrict__ Cb) {
    __shared__ __align__(16) unsigned short As[128 * 64];
    __shared__ __align__(16) unsigned short Bs[128 * 64];
    constexpr int GX  = N / 128;         // blocks along n: 12 (QKV)
    constexpr int PER = (GX * 256) / 8;  // blocks per XCD (exact: nwg % 8 == 0)
    const int wgid = blockIdx.y * GX + blockIdx.x;          // dispatch-linear
    const int swz  = (wgid & 7) * PER + (wgid >> 3);        // bijective chunking
    const int bm = swz / GX;
    const int bn = swz % GX;

    const int tid = threadIdx.x;
    const int wave = tid >> 6, lane = tid & 63;
    const int quad = lane >> 4, l16 = lane & 15;
    const int wm = (wave >> 1) * 64, wn = (wave & 1) * 64;
    // DMA: chunk = 8 rows x 64 cols = 1 KB. Lane covers row chunk*8+(lane>>3),
    // stored col-block lane&7, which must hold source col-block (lane&7)^(row&7).
    const int srow = lane >> 3;                  // 0..7 within chunk
    const int scol = ((lane & 7) ^ srow) * 8;    // swizzled source column

    float4v acc[4][4] = {};

    const unsigned short* Abase = A + (size_t)(bm * 128) * KDIM;
    const unsigned short* Bbase = B + (size_t)(bn * 128) * KDIM;

    for (int k0 = 0; k0 < KDIM; k0 += 64) {
        #pragma unroll
        for (int j = 0; j < 4; j++) {
            int chunk = j * 4 + wave;               // 0..15
            int row = chunk * 8 + srow;             // 0..127
            gl2lds16(Abase + (size_t)row * KDIM + k0 + scol, As + chunk * 512);
            gl2lds16(Bbase + (size_t)row * KDIM + k0 + scol, Bs + chunk * 512);
        }
        __syncthreads();
        #pragma unroll
        for (int ki = 0; ki < 2; ki++) {
            short8 af[4], bf[4];
            #pragma unroll
            for (int mi = 0; mi < 4; mi++) {
                int r = wm + mi * 16 + l16;
                int blk = (ki * 4 + quad) ^ (l16 & 7);
                af[mi] = *(const short8*)(As + r * 64 + blk * 8);
            }
            #pragma unroll
            for (int ni = 0; ni < 4; ni++) {
                int r = wn + ni * 16 + l16;
                int blk = (ki * 4 + quad) ^ (l16 & 7);
                bf[ni] = *(const short8*)(Bs + r * 64 + blk * 8);
            }
            #pragma unroll
            for (int mi = 0; mi < 4; mi++)
                #pragma unroll
                for (int ni = 0; ni < 4; ni++)
                    acc[mi][ni] = __builtin_amdgcn_mfma_f32_16x16x32_bf16(
                        af[mi], bf[ni], acc[mi][ni], 0, 0, 0);
        }
        __syncthreads();
    }

    #pragma unroll
    for (int mi = 0; mi < 4; mi++) {
        #pragma unroll
        for (int r = 0; r < 4; r++) {
            int m = bm * 128 + wm + mi * 16 + quad * 4 + r;
            #pragma unroll
            for (int ni = 0; ni < 4; ni++) {
                int n = bn * 128 + wn + ni * 16 + l16;
                Cb[(size_t)m * N + n] = f2bf(acc[mi][ni][r]);
            }
        }
    }
}

// ---------------- fused attention + projection, one (WINDOW, HEAD-HALF) per block
// Round-10 version (full window/block) measured 77 us with Occupancy 19%:
// 131.5 KB LDS -> 1 block/CU -> 2 waves/SIMD, nothing to hide barrier drains.
// Split exploits: proj-input rows lw = h*8 + w/8 partition by head half, and
// C = Asf@W^T rows are independent -> block (win, half) computes heads
// half*4..half*4+3 for all 64 tokens, Asf half = 32 rows = 32 KB, KV staged in
// 4 chunks of 16 tokens (33 KB). LDS 65.8 KB -> 2 blocks/CU, grid 1024.
// Phase 1 map: tid -> (dq = tid&7: 8-elem d-chunk, h = (tid>>3)&3, tl = tid>>5:
// token 0..15 of chunk). S partials merged via 3x __shfl_xor (dq = low lane
// bits); K reads are 16 addr x 4-lane broadcast, 2-way max = free. All 4 Q
// loads hoisted to kernel start. Asf write: bank-group = dq^h^e -> uniform
// 8 lanes/group = minimum. Phase 2: C[32x512], 8 waves x 64-col strips,
// acc 2x4, B-fragments straight from global (wprojb L2-resident).
// XCD swizzle (nwg=1024, %8==0) keeps a window's two halves on one XCD.
#define KVS 1032   // padded row stride (elems): 2064 B = 516 dw = +4 banks/row
__global__ __launch_bounds__(512, 4) void attnproj_kernel(
        const unsigned short* __restrict__ qkvb,
        const unsigned short* __restrict__ wprojb,
        const float* __restrict__ bias,
        float* __restrict__ out) {
    __shared__ __align__(16) unsigned short Asf[32 * 512];   // 32 KB
    __shared__ __align__(16) unsigned short KV[16 * KVS];    // 33 KB
    const int tid = threadIdx.x;
    const int bid = blockIdx.x;                   // 1024 blocks
    const int swzb = (bid & 7) * 128 + (bid >> 3);
    const int win = swzb >> 1, half = swzb & 1;

    // ======================= phase 1: attention (4 heads) =======================
    {
        const int dq = tid & 7;          // d-chunk (8 elems)
        const int h  = (tid >> 3) & 3;   // local head
        const int tl = tid >> 5;         // token 0..15 within chunk
        const int hg = half * 4 + h;     // global head

        // hoist all 4 chunks' Q loads (issue before any staging)
        short8 qs[4];
        #pragma unroll
        for (int c = 0; c < 4; c++)
            qs[c] = *(const short8*)(qkvb + (size_t)(win * 64 + c * 16 + tl) * NQKV
                                     + hg * 64 + dq * 8);

        #pragma unroll
        for (int c = 0; c < 4; c++) {
            // DMA-stage K/V of this chunk's 16 tokens (cols 512..1535)
            #pragma unroll
            for (int i = 0; i < 4; i++) {
                int slot = i * 512 + tid;            // 0..2047
                int row = slot >> 7, c8 = slot & 127;
                gl2lds16(qkvb + (size_t)(win * 64 + c * 16 + row) * NQKV + 512 + c8 * 8,
                         KV + row * KVS + c8 * 8);
            }
            __syncthreads();

            const unsigned short* krow = KV + tl * KVS;
            const int w = c * 16 + tl;

            float qv[8];
            #pragma unroll
            for (int j = 0; j < 8; j++)
                qv[j] = bf2f((unsigned short)qs[c][j]);

            // S[g] = Q_hg . K_g : 8-d partial, butterfly-merge over dq group
            float s[8];
            #pragma unroll
            for (int g = 0; g < 8; g++) {
                float acc = 0.f;
                short8 ks = *(const short8*)(krow + g * 64 + dq * 8);
                #pragma unroll
                for (int j = 0; j < 8; j++)
                    acc += qv[j] * bf2f((unsigned short)ks[j]);
                acc += __shfl_xor(acc, 1);
                acc += __shfl_xor(acc, 2);
                acc += __shfl_xor(acc, 4);
                s[g] = acc;
            }

            float mx = s[0];
            #pragma unroll
            for (int g = 1; g < 8; g++) mx = fmaxf(mx, s[g]);
            float p[8], sum = 0.f;
            #pragma unroll
            for (int g = 0; g < 8; g++) { p[g] = __expf((s[g] - mx) * 0.125f); sum += p[g]; }
            float inv = 1.f / sum;
            #pragma unroll
            for (int g = 0; g < 8; g++) p[g] *= inv;

            // O[dq-chunk] = sum_g P[g] V[g]
            float o[8];
            #pragma unroll
            for (int j = 0; j < 8; j++) o[j] = 0.f;
            #pragma unroll
            for (int g = 0; g < 8; g++) {
                short8 vs = *(const short8*)(krow + 512 + g * 64 + dq * 8);
                #pragma unroll
                for (int j = 0; j < 8; j++)
                    o[j] += p[g] * bf2f((unsigned short)vs[j]);
            }

            // write to Asf (local rows 0..31), swizzled
            int r = h * 8 + (w >> 3);                // local proj row
            int keyr = (r ^ (r >> 3)) & 7;
            short8 pk;
            #pragma unroll
            for (int j = 0; j < 8; j++) pk[j] = (short)f2bf(o[j]);
            int cb = (w & 7) * 8 + dq;               // logical col-block 0..63
            *(short8*)(Asf + r * 512 + ((cb ^ keyr) * 8)) = pk;
            __syncthreads();   // KV reuse + Asf consistency
        }
    }

    // ======================= phase 2: projection GEMM (32x512) ==================
    const int wave = tid >> 6, lane = tid & 63;
    const int quad = lane >> 4, l16 = lane & 15;
    const int wc = wave;                            // cols [wc*64, wc*64+64)

    float4v acc[2][4] = {};
    #pragma unroll
    for (int ks = 0; ks < 16; ks++) {               // BK = 32 per MFMA K
        short8 af[2], bfr[4];
        #pragma unroll
        for (int mi = 0; mi < 2; mi++) {
            int r = mi * 16 + l16;                  // A row 0..31
            int kb = ks * 4 + quad;                 // logical k-block 0..63
            af[mi] = *(const short8*)(Asf + r * 512 + ((kb ^ ((r ^ (r >> 3)) & 7)) * 8));
        }
        #pragma unroll
        for (int ni = 0; ni < 4; ni++) {
            int r = wc * 64 + ni * 16 + l16;        // B (n) row
            bfr[ni] = *(const short8*)(wprojb + (size_t)r * KDIM + ks * 32 + quad * 8);
        }
        #pragma unroll
        for (int mi = 0; mi < 2; mi++)
            #pragma unroll
            for (int ni = 0; ni < 4; ni++)
                acc[mi][ni] = __builtin_amdgcn_mfma_f32_16x16x32_bf16(
                    af[mi], bfr[ni], acc[mi][ni], 0, 0, 0);
    }

    // epilogue: bias + roll(+32) + f32 store
    #pragma unroll
    for (int mi = 0; mi < 2; mi++) {
        #pragma unroll
        for (int r4 = 0; r4 < 4; r4++) {
            int m = win * 64 + half * 32 + mi * 16 + quad * 4 + r4;
            int b = m >> 12, pp = m & 4095;
            int nrow = (pp + 32) & 4095;            // roll(out, +32)
            float* orow = out + (((size_t)((b << 12) | nrow)) << 9);
            #pragma unroll
            for (int ni = 0; ni < 4; ni++) {
                int n = wc * 64 + ni * 16 + l16;
                orow[n] = acc[mi][ni][r4] + bias[n];
            }
        }
    }
}

extern "C" void kernel_launch(void* const* d_in, const int* in_sizes, int n_in,
                              void* d_out, int out_size, void* d_ws, size_t ws_size,
                              hipStream_t stream) {
    const float* x      = (const float*)d_in[0];
    const float* w_qkv  = (const float*)d_in[1];
    const float* w_proj = (const float*)d_in[2];
    const float* b_proj = (const float*)d_in[3];
    float* out = (float*)d_out;

    char* ws = (char*)d_ws;
    unsigned short* xb     = (unsigned short*)(ws);                 // 32 MB
    unsigned short* wqkvb  = (unsigned short*)(ws + 33554432);      // 1.5 MB
    unsigned short* wprojb = (unsigned short*)(ws + 35127296);      // 0.5 MB
    unsigned short* qkvb   = (unsigned short*)(ws + 35651584);      // 96 MB

    cast_all_kernel<<<17408, 256, 0, stream>>>(x, w_qkv, w_proj, xb, wqkvb, wprojb);
    gemm_kernel<NQKV><<<dim3(12, 256), 256, 0, stream>>>(xb, wqkvb, qkvb);
    attnproj_kernel<<<1024, 512, 0, stream>>>(qkvb, wprojb, b_proj, out);
}